// Round 2
// baseline (662.869 us; speedup 1.0000x reference)
//
#include <hip/hip_runtime.h>
#include <hip/hip_bf16.h>
#include <math.h>

#define N_V 100000
#define N_E 600000
#define N_F 200000
// CIN = COUT = 128, H = 32

typedef __attribute__((ext_vector_type(8))) short bf16x8;
typedef __attribute__((ext_vector_type(4))) float f32x4;

#define GEMM_WAVES (N_V / 16)          // 6250
#define GEMM_BLOCKS ((GEMM_WAVES + 3) / 4)  // 1563

__device__ __forceinline__ unsigned short f2bf(float f) {
    unsigned int u = __builtin_bit_cast(unsigned int, f);
    u += 0x7fffu + ((u >> 16) & 1u);   // round-to-nearest-even
    return (unsigned short)(u >> 16);
}

// --- K0a: in-degree histogram ---
__global__ void k_count(const int* __restrict__ edges, int* __restrict__ cnt) {
    int e = blockIdx.x * blockDim.x + threadIdx.x;
    if (e < N_E) atomicAdd(&cnt[edges[N_E + e]], 1);
}

// --- K0b: single-block exclusive scan -> row_start; cnt becomes cursor ---
__global__ __launch_bounds__(1024) void k_scan(int* __restrict__ cnt, int* __restrict__ row_start) {
    __shared__ int sp[1024];
    int t = threadIdx.x;
    int begin = t * 98, end = min(begin + 98, N_V);
    int s = 0;
    for (int i = begin; i < end; i++) s += cnt[i];
    sp[t] = s; __syncthreads();
    for (int off = 1; off < 1024; off <<= 1) {
        int v = (t >= off) ? sp[t - off] : 0;
        __syncthreads();
        sp[t] += v;
        __syncthreads();
    }
    int run = sp[t] - s;               // exclusive base
    for (int i = begin; i < end; i++) {
        int c = cnt[i];
        row_start[i] = run;
        cnt[i] = run;                  // cursor init
        run += c;
    }
    if (t == 1023) row_start[N_V] = run;
}

// --- K1: face normals, atomic scatter-add ---
__global__ void k_face_normals(const float* __restrict__ vtx,
                               const int* __restrict__ faces,
                               float* __restrict__ nrm) {
    int f = blockIdx.x * blockDim.x + threadIdx.x;
    if (f >= N_F) return;
    int i0 = faces[f], i1 = faces[N_F + f], i2 = faces[2 * N_F + f];
    float ax = vtx[3 * i0], ay = vtx[3 * i0 + 1], az = vtx[3 * i0 + 2];
    float bx = vtx[3 * i1] - ax, by = vtx[3 * i1 + 1] - ay, bz = vtx[3 * i1 + 2] - az;
    float cx = vtx[3 * i2] - ax, cy = vtx[3 * i2 + 1] - ay, cz = vtx[3 * i2 + 2] - az;
    float nx = by * cz - bz * cy;
    float ny = bz * cx - bx * cz;
    float nz = bx * cy - by * cx;
    atomicAdd(&nrm[3 * i0 + 0], nx); atomicAdd(&nrm[3 * i0 + 1], ny); atomicAdd(&nrm[3 * i0 + 2], nz);
    atomicAdd(&nrm[3 * i1 + 0], nx); atomicAdd(&nrm[3 * i1 + 1], ny); atomicAdd(&nrm[3 * i1 + 2], nz);
    atomicAdd(&nrm[3 * i2 + 0], nx); atomicAdd(&nrm[3 * i2 + 1], ny); atomicAdd(&nrm[3 * i2 + 2], nz);
}

// --- K2: normalize vertex normals ---
__global__ void k_norm_normals(float* __restrict__ nrm) {
    int i = blockIdx.x * blockDim.x + threadIdx.x;
    if (i >= N_V) return;
    float x = nrm[3 * i], y = nrm[3 * i + 1], z = nrm[3 * i + 2];
    float inv = 1.f / (sqrtf(x * x + y * y + z * z) + 1e-8f);
    nrm[3 * i] = x * inv; nrm[3 * i + 1] = y * inv; nrm[3 * i + 2] = z * inv;
}

// --- K3: per-edge MLP -> w; fill CSR slot via cursor atomic ---
__global__ void k_edge(const float* __restrict__ vtx, const int* __restrict__ edges,
                       const float* __restrict__ nrm,
                       const float* __restrict__ W1, const float* __restrict__ b1,
                       const float* __restrict__ W2, const float* __restrict__ b2,
                       int* __restrict__ cursor, int* __restrict__ csr_src,
                       float* __restrict__ csr_w) {
    __shared__ float sW1[96], sb1[32], sW2[192], sb2[6];
    int t = threadIdx.x;
    if (t < 96)  sW1[t] = W1[t];
    if (t < 32)  sb1[t] = b1[t];
    if (t < 192) sW2[t] = W2[t];
    if (t < 6)   sb2[t] = b2[t];
    __syncthreads();
    int e = blockIdx.x * blockDim.x + t;
    if (e >= N_E) return;
    int s = edges[e], d = edges[N_E + e];
    float dx = vtx[3 * d] - vtx[3 * s];
    float dy = vtx[3 * d + 1] - vtx[3 * s + 1];
    float dz = vtx[3 * d + 2] - vtx[3 * s + 2];
    float nx = nrm[3 * s], ny = nrm[3 * s + 1], nz = nrm[3 * s + 2];
    float dp = dx * nx + dy * ny + dz * nz;
    float tx = dx - dp * nx, ty = dy - dp * ny, tz = dz - dp * nz;
    float th0 = sb2[0], th1 = sb2[1], th2 = sb2[2], th3 = sb2[3], th4 = sb2[4], th5 = sb2[5];
    #pragma unroll
    for (int j = 0; j < 32; j++) {
        float h = tx * sW1[j] + ty * sW1[32 + j] + tz * sW1[64 + j] + sb1[j];
        h = fmaxf(h, 0.f);
        const float* w2r = &sW2[j * 6];
        th0 += h * w2r[0]; th1 += h * w2r[1]; th2 += h * w2r[2];
        th3 += h * w2r[3]; th4 += h * w2r[4]; th5 += h * w2r[5];
    }
    float ux = th0 * tx + th1 * ty + th2 * tz;
    float uy = th1 * tx + th3 * ty + th4 * tz;
    float uz = th2 * tx + th4 * ty + th5 * tz;
    float q = ux * ux + uy * uy + uz * uz;
    float w = expf(-q);
    int slot = atomicAdd(&cursor[d], 1);
    csr_src[slot] = s;
    csr_w[slot] = w;
}

// --- K4: CSR gather-aggregate. One wave per vertex; lane owns 2 cols.
// Writes A = num/den' (fp32) into out, gf[v] = den/den'.
__global__ __launch_bounds__(256) void k_agg(const float* __restrict__ feat,
                                             const int* __restrict__ row_start,
                                             const int* __restrict__ csr_src,
                                             const float* __restrict__ csr_w,
                                             float* __restrict__ out,
                                             float* __restrict__ gf) {
    int v = blockIdx.x * 4 + (threadIdx.x >> 6);
    if (v >= N_V) return;
    int lane = threadIdx.x & 63;
    int base = row_start[v], end = row_start[v + 1];
    float ax = 0.f, ay = 0.f, den = 0.f;
    for (int i = base; i < end; i++) {
        int s = csr_src[i];
        float w = csr_w[i];
        float2 f = *(const float2*)(feat + (size_t)s * 128 + 2 * lane);
        ax += w * f.x; ay += w * f.y; den += w;
    }
    float inv = 1.f / (den + 1e-5f);
    float2 o; o.x = ax * inv; o.y = ay * inv;
    *(float2*)(out + (size_t)v * 128 + 2 * lane) = o;
    if (lane == 0) gf[v] = den * inv;
}

// --- K5: pack Wlin into bf16 MFMA B-fragment order ---
__global__ void k_pack_w(const float* __restrict__ Wlin, unsigned short* __restrict__ Wb) {
    int t = blockIdx.x * blockDim.x + threadIdx.x;
    if (t >= 16384) return;
    int j = t & 7;
    int lane = (t >> 3) & 63;
    int ct = (t >> 9) & 7;
    int kk = t >> 12;
    int k = kk * 32 + (lane >> 4) * 8 + j;
    int n = ct * 16 + (lane & 15);
    Wb[t] = f2bf(Wlin[k * 128 + n]);
}

// --- K6: in-place GEMM out = A @ Wlin + blin*gf, fused column-stats partials ---
__global__ __launch_bounds__(256) void k_gemm(float* __restrict__ out,
                                              const float* __restrict__ gf,
                                              const unsigned short* __restrict__ Wb,
                                              const float* __restrict__ blin,
                                              float* __restrict__ partials) {
    __shared__ float ldsS[128], ldsQ[128];
    int t = threadIdx.x;
    if (t < 128) { ldsS[t] = 0.f; ldsQ[t] = 0.f; }
    __syncthreads();

    int wave = (blockIdx.x * 256 + t) >> 6;
    int lane = t & 63;
    int m = lane & 15, quad = lane >> 4;
    if (wave < GEMM_WAVES) {
        int r0 = wave * 16;
        const float* arow = out + (size_t)(r0 + m) * 128;
        f32x4 acc[8];
        #pragma unroll
        for (int ct = 0; ct < 8; ct++) acc[ct] = (f32x4){0.f, 0.f, 0.f, 0.f};
        #pragma unroll
        for (int kk = 0; kk < 4; kk++) {
            int k0 = kk * 32 + quad * 8;
            float4 a0 = *(const float4*)(arow + k0);
            float4 a1 = *(const float4*)(arow + k0 + 4);
            bf16x8 af;
            af[0] = (short)f2bf(a0.x); af[1] = (short)f2bf(a0.y);
            af[2] = (short)f2bf(a0.z); af[3] = (short)f2bf(a0.w);
            af[4] = (short)f2bf(a1.x); af[5] = (short)f2bf(a1.y);
            af[6] = (short)f2bf(a1.z); af[7] = (short)f2bf(a1.w);
            #pragma unroll
            for (int ct = 0; ct < 8; ct++) {
                bf16x8 bfv = *(const bf16x8*)(Wb + (((kk * 8 + ct) * 64 + lane) << 3));
                acc[ct] = __builtin_amdgcn_mfma_f32_16x16x32_bf16(af, bfv, acc[ct], 0, 0, 0);
            }
        }
        float g0 = gf[r0 + quad * 4 + 0];
        float g1 = gf[r0 + quad * 4 + 1];
        float g2 = gf[r0 + quad * 4 + 2];
        float g3 = gf[r0 + quad * 4 + 3];
        #pragma unroll
        for (int ct = 0; ct < 8; ct++) {
            int c = ct * 16 + m;
            float bl = blin[c];
            float gr[4] = {g0, g1, g2, g3};
            float ss = 0.f, qq = 0.f;
            #pragma unroll
            for (int reg = 0; reg < 4; reg++) {
                int r = r0 + quad * 4 + reg;
                float val = acc[ct][reg] + bl * gr[reg];
                out[(size_t)r * 128 + c] = val;
                ss += val; qq += val * val;
            }
            ss += __shfl_xor(ss, 16); qq += __shfl_xor(qq, 16);
            ss += __shfl_xor(ss, 32); qq += __shfl_xor(qq, 32);
            if (quad == 0) {
                atomicAdd(&ldsS[ct * 16 + m], ss);
                atomicAdd(&ldsQ[ct * 16 + m], qq);
            }
        }
    }
    __syncthreads();
    if (t < 128)        partials[(size_t)blockIdx.x * 256 + t] = ldsS[t];
    else                partials[(size_t)blockIdx.x * 256 + t] = ldsQ[t - 128];
}

// --- K7: reduce per-block partials -> stats[c]=mu, stats[128+c]=1/(sd+eps) ---
__global__ __launch_bounds__(256) void k_rstats(const float* __restrict__ partials,
                                                float* __restrict__ stats) {
    __shared__ float lds[256];
    int t = threadIdx.x;
    float s0 = 0.f, s1 = 0.f, s2 = 0.f, s3 = 0.f;
    int b = 0;
    for (; b + 4 <= GEMM_BLOCKS; b += 4) {
        s0 += partials[(size_t)(b + 0) * 256 + t];
        s1 += partials[(size_t)(b + 1) * 256 + t];
        s2 += partials[(size_t)(b + 2) * 256 + t];
        s3 += partials[(size_t)(b + 3) * 256 + t];
    }
    for (; b < GEMM_BLOCKS; b++) s0 += partials[(size_t)b * 256 + t];
    lds[t] = s0 + s1 + s2 + s3;
    __syncthreads();
    if (t < 128) {
        float sum = lds[t], sq = lds[128 + t];
        float mu = sum * (1.f / N_V);
        float var = (sq - sum * mu) * (1.f / (N_V - 1));
        float sd = sqrtf(fmaxf(var, 0.f));
        stats[t] = mu;
        stats[128 + t] = 1.f / (sd + 1e-5f);
    }
}

// --- K8: normalize + ELU, in place, float4 ---
__global__ void k_finalize(float* __restrict__ out, const float* __restrict__ stats) {
    int i = blockIdx.x * blockDim.x + threadIdx.x;
    if (i >= N_V * 32) return;
    float4 v = ((float4*)out)[i];
    int c0 = (i * 4) & 127;
    float mu0 = stats[c0], mu1 = stats[c0 + 1], mu2 = stats[c0 + 2], mu3 = stats[c0 + 3];
    float is0 = stats[128 + c0], is1 = stats[128 + c0 + 1], is2 = stats[128 + c0 + 2], is3 = stats[128 + c0 + 3];
    v.x = (v.x - mu0) * is0; v.y = (v.y - mu1) * is1;
    v.z = (v.z - mu2) * is2; v.w = (v.w - mu3) * is3;
    v.x = v.x > 0.f ? v.x : expm1f(v.x);
    v.y = v.y > 0.f ? v.y : expm1f(v.y);
    v.z = v.z > 0.f ? v.z : expm1f(v.z);
    v.w = v.w > 0.f ? v.w : expm1f(v.w);
    ((float4*)out)[i] = v;
}

extern "C" void kernel_launch(void* const* d_in, const int* in_sizes, int n_in,
                              void* d_out, int out_size, void* d_ws, size_t ws_size,
                              hipStream_t stream) {
    const float* feat  = (const float*)d_in[0];
    const float* vtx   = (const float*)d_in[1];
    const int*   edges = (const int*)d_in[2];
    const int*   faces = (const int*)d_in[3];
    const float* W1   = (const float*)d_in[4];
    const float* b1   = (const float*)d_in[5];
    const float* W2   = (const float*)d_in[6];
    const float* b2   = (const float*)d_in[7];
    const float* Wlin = (const float*)d_in[8];
    const float* blin = (const float*)d_in[9];
    float* out = (float*)d_out;

    float* ws = (float*)d_ws;
    // layout (float offsets):
    float* nrm        = ws;                          // 300000
    int*   cnt        = (int*)(ws + 300000);         // 100000 (becomes cursor)
    int*   row_start  = (int*)(ws + 400000);         // 100001
    float* gf         = ws + 500004;                 // 100000 (reused as stats)
    unsigned short* Wb = (unsigned short*)(ws + 600004); // 16384 shorts (8192 f)
    int*   csr_src    = (int*)(ws + 608196);         // 600000
    float* csr_w      = ws + 1208196;                // 600000
    float* partials   = ws + 1808196;                // 1563*256 = 400128
    float* stats      = gf;                          // alias (gf consumed by k_gemm)

    // zero nrm + cnt in one shot
    hipMemsetAsync(d_ws, 0, 400000 * sizeof(float), stream);

    k_count<<<(N_E + 255) / 256, 256, 0, stream>>>(edges, cnt);
    k_face_normals<<<(N_F + 255) / 256, 256, 0, stream>>>(vtx, faces, nrm);
    k_norm_normals<<<(N_V + 255) / 256, 256, 0, stream>>>(nrm);
    k_scan<<<1, 1024, 0, stream>>>(cnt, row_start);
    k_pack_w<<<64, 256, 0, stream>>>(Wlin, Wb);
    k_edge<<<(N_E + 255) / 256, 256, 0, stream>>>(vtx, edges, nrm, W1, b1, W2, b2,
                                                  cnt, csr_src, csr_w);
    k_agg<<<N_V / 4, 256, 0, stream>>>(feat, row_start, csr_src, csr_w, out, gf);
    k_gemm<<<GEMM_BLOCKS, 256, 0, stream>>>(out, gf, Wb, blin, partials);
    k_rstats<<<1, 256, 0, stream>>>(partials, stats);
    k_finalize<<<(N_V * 32 + 255) / 256, 256, 0, stream>>>(out, stats);
}

// Round 4
// 422.461 us; speedup vs baseline: 1.5691x; 1.5691x over previous
//
#include <hip/hip_runtime.h>
#include <hip/hip_bf16.h>
#include <math.h>

#define N_V 100000
#define N_E 600000
#define N_F 200000
// CIN = COUT = 128, H = 32

typedef __attribute__((ext_vector_type(8))) short bf16x8;
typedef __attribute__((ext_vector_type(4))) float f32x4;

#define GEMM_WAVES (N_V / 16)               // 6250
#define GEMM_BLOCKS ((GEMM_WAVES + 3) / 4)  // 1563
#define SCAN_BLOCKS 98                      // 98 * 1024 >= N_V

__device__ __forceinline__ unsigned short f2bf(float f) {
    unsigned int u = __builtin_bit_cast(unsigned int, f);
    u += 0x7fffu + ((u >> 16) & 1u);   // round-to-nearest-even
    return (unsigned short)(u >> 16);
}

// --- K0a: in-degree histogram ---
__global__ void k_count(const int* __restrict__ edges, int* __restrict__ cnt) {
    int e = blockIdx.x * blockDim.x + threadIdx.x;
    if (e < N_E) atomicAdd(&cnt[edges[N_E + e]], 1);
}

// --- K0b: per-block exclusive scan (1024 elems/block) + block sums ---
__global__ __launch_bounds__(1024) void k_scan1(const int* __restrict__ cnt,
                                                int* __restrict__ eprefix,
                                                int* __restrict__ bsum) {
    __shared__ int sp[1024];
    int t = threadIdx.x;
    int i = blockIdx.x * 1024 + t;
    int v = (i < N_V) ? cnt[i] : 0;
    sp[t] = v; __syncthreads();
    #pragma unroll
    for (int off = 1; off < 1024; off <<= 1) {
        int u = (t >= off) ? sp[t - off] : 0;
        __syncthreads();
        sp[t] += u;
        __syncthreads();
    }
    if (i < N_V) eprefix[i] = sp[t] - v;
    if (t == 1023) bsum[blockIdx.x] = sp[1023];
}

// --- K0c: exclusive scan of 98 block sums (1 tiny block) ---
__global__ __launch_bounds__(128) void k_scan2(int* __restrict__ bsum) {
    __shared__ int sp[128];
    int t = threadIdx.x;
    int v = (t < SCAN_BLOCKS) ? bsum[t] : 0;
    sp[t] = v; __syncthreads();
    #pragma unroll
    for (int off = 1; off < 128; off <<= 1) {
        int u = (t >= off) ? sp[t - off] : 0;
        __syncthreads();
        sp[t] += u;
        __syncthreads();
    }
    if (t < SCAN_BLOCKS) bsum[t] = sp[t] - v;
}

// --- K0d: row_start = eprefix + block offset; init cursor ---
__global__ void k_scan3(const int* __restrict__ eprefix, const int* __restrict__ bsum,
                        int* __restrict__ row_start, int* __restrict__ cursor) {
    int i = blockIdx.x * blockDim.x + threadIdx.x;
    if (i >= N_V) return;
    int r = eprefix[i] + bsum[i >> 10];
    row_start[i] = r;
    cursor[i] = r;
    if (i == 0) row_start[N_V] = N_E;
}

// --- K1: face normals, atomic scatter-add ---
__global__ void k_face_normals(const float* __restrict__ vtx,
                               const int* __restrict__ faces,
                               float* __restrict__ nrm) {
    int f = blockIdx.x * blockDim.x + threadIdx.x;
    if (f >= N_F) return;
    int i0 = faces[f], i1 = faces[N_F + f], i2 = faces[2 * N_F + f];
    float ax = vtx[3 * i0], ay = vtx[3 * i0 + 1], az = vtx[3 * i0 + 2];
    float bx = vtx[3 * i1] - ax, by = vtx[3 * i1 + 1] - ay, bz = vtx[3 * i1 + 2] - az;
    float cx = vtx[3 * i2] - ax, cy = vtx[3 * i2 + 1] - ay, cz = vtx[3 * i2 + 2] - az;
    float nx = by * cz - bz * cy;
    float ny = bz * cx - bx * cz;
    float nz = bx * cy - by * cx;
    atomicAdd(&nrm[3 * i0 + 0], nx); atomicAdd(&nrm[3 * i0 + 1], ny); atomicAdd(&nrm[3 * i0 + 2], nz);
    atomicAdd(&nrm[3 * i1 + 0], nx); atomicAdd(&nrm[3 * i1 + 1], ny); atomicAdd(&nrm[3 * i1 + 2], nz);
    atomicAdd(&nrm[3 * i2 + 0], nx); atomicAdd(&nrm[3 * i2 + 1], ny); atomicAdd(&nrm[3 * i2 + 2], nz);
}

// --- K2: normalize vertex normals ---
__global__ void k_norm_normals(float* __restrict__ nrm) {
    int i = blockIdx.x * blockDim.x + threadIdx.x;
    if (i >= N_V) return;
    float x = nrm[3 * i], y = nrm[3 * i + 1], z = nrm[3 * i + 2];
    float inv = 1.f / (sqrtf(x * x + y * y + z * z) + 1e-8f);
    nrm[3 * i] = x * inv; nrm[3 * i + 1] = y * inv; nrm[3 * i + 2] = z * inv;
}

// --- K3: per-edge MLP -> w; fill CSR slot via cursor atomic ---
__global__ void k_edge(const float* __restrict__ vtx, const int* __restrict__ edges,
                       const float* __restrict__ nrm,
                       const float* __restrict__ W1, const float* __restrict__ b1,
                       const float* __restrict__ W2, const float* __restrict__ b2,
                       int* __restrict__ cursor, int* __restrict__ csr_src,
                       float* __restrict__ csr_w) {
    __shared__ float sW1[96], sb1[32], sW2[192], sb2[6];
    int t = threadIdx.x;
    if (t < 96)  sW1[t] = W1[t];
    if (t < 32)  sb1[t] = b1[t];
    if (t < 192) sW2[t] = W2[t];
    if (t < 6)   sb2[t] = b2[t];
    __syncthreads();
    int e = blockIdx.x * blockDim.x + t;
    if (e >= N_E) return;
    int s = edges[e], d = edges[N_E + e];
    float dx = vtx[3 * d] - vtx[3 * s];
    float dy = vtx[3 * d + 1] - vtx[3 * s + 1];
    float dz = vtx[3 * d + 2] - vtx[3 * s + 2];
    float nx = nrm[3 * s], ny = nrm[3 * s + 1], nz = nrm[3 * s + 2];
    float dp = dx * nx + dy * ny + dz * nz;
    float tx = dx - dp * nx, ty = dy - dp * ny, tz = dz - dp * nz;
    float th0 = sb2[0], th1 = sb2[1], th2 = sb2[2], th3 = sb2[3], th4 = sb2[4], th5 = sb2[5];
    #pragma unroll
    for (int j = 0; j < 32; j++) {
        float h = tx * sW1[j] + ty * sW1[32 + j] + tz * sW1[64 + j] + sb1[j];
        h = fmaxf(h, 0.f);
        const float* w2r = &sW2[j * 6];
        th0 += h * w2r[0]; th1 += h * w2r[1]; th2 += h * w2r[2];
        th3 += h * w2r[3]; th4 += h * w2r[4]; th5 += h * w2r[5];
    }
    float ux = th0 * tx + th1 * ty + th2 * tz;
    float uy = th1 * tx + th3 * ty + th4 * tz;
    float uz = th2 * tx + th4 * ty + th5 * tz;
    float q = ux * ux + uy * uy + uz * uz;
    float w = expf(-q);
    int slot = atomicAdd(&cursor[d], 1);
    csr_src[slot] = s;
    csr_w[slot] = w;
}

// --- K4: CSR gather-aggregate. One wave per vertex; lane owns 2 cols. ---
__global__ __launch_bounds__(256) void k_agg(const float* __restrict__ feat,
                                             const int* __restrict__ row_start,
                                             const int* __restrict__ csr_src,
                                             const float* __restrict__ csr_w,
                                             float* __restrict__ out,
                                             float* __restrict__ gf) {
    int v = blockIdx.x * 4 + (threadIdx.x >> 6);
    if (v >= N_V) return;
    int lane = threadIdx.x & 63;
    int base = row_start[v], end = row_start[v + 1];
    float ax = 0.f, ay = 0.f, den = 0.f;
    for (int i = base; i < end; i++) {
        int s = csr_src[i];
        float w = csr_w[i];
        float2 f = *(const float2*)(feat + (size_t)s * 128 + 2 * lane);
        ax += w * f.x; ay += w * f.y; den += w;
    }
    float inv = 1.f / (den + 1e-5f);
    float2 o; o.x = ax * inv; o.y = ay * inv;
    *(float2*)(out + (size_t)v * 128 + 2 * lane) = o;
    if (lane == 0) gf[v] = den * inv;
}

// --- K5: pack Wlin into bf16 MFMA B-fragment order ---
__global__ void k_pack_w(const float* __restrict__ Wlin, unsigned short* __restrict__ Wb) {
    int t = blockIdx.x * blockDim.x + threadIdx.x;
    if (t >= 16384) return;
    int j = t & 7;
    int lane = (t >> 3) & 63;
    int ct = (t >> 9) & 7;
    int kk = t >> 12;
    int k = kk * 32 + (lane >> 4) * 8 + j;
    int n = ct * 16 + (lane & 15);
    Wb[t] = f2bf(Wlin[k * 128 + n]);
}

// --- K6: in-place GEMM out = A @ Wlin + blin*gf, fused column-stats partials ---
__global__ __launch_bounds__(256) void k_gemm(float* __restrict__ out,
                                              const float* __restrict__ gf,
                                              const unsigned short* __restrict__ Wb,
                                              const float* __restrict__ blin,
                                              float* __restrict__ partials) {
    __shared__ float ldsS[128], ldsQ[128];
    int t = threadIdx.x;
    if (t < 128) { ldsS[t] = 0.f; ldsQ[t] = 0.f; }
    __syncthreads();

    int wave = (blockIdx.x * 256 + t) >> 6;
    int lane = t & 63;
    int m = lane & 15, quad = lane >> 4;
    if (wave < GEMM_WAVES) {
        int r0 = wave * 16;
        const float* arow = out + (size_t)(r0 + m) * 128;
        f32x4 acc[8];
        #pragma unroll
        for (int ct = 0; ct < 8; ct++) acc[ct] = (f32x4){0.f, 0.f, 0.f, 0.f};
        #pragma unroll
        for (int kk = 0; kk < 4; kk++) {
            int k0 = kk * 32 + quad * 8;
            float4 a0 = *(const float4*)(arow + k0);
            float4 a1 = *(const float4*)(arow + k0 + 4);
            bf16x8 af;
            af[0] = (short)f2bf(a0.x); af[1] = (short)f2bf(a0.y);
            af[2] = (short)f2bf(a0.z); af[3] = (short)f2bf(a0.w);
            af[4] = (short)f2bf(a1.x); af[5] = (short)f2bf(a1.y);
            af[6] = (short)f2bf(a1.z); af[7] = (short)f2bf(a1.w);
            #pragma unroll
            for (int ct = 0; ct < 8; ct++) {
                bf16x8 bfv = *(const bf16x8*)(Wb + (((kk * 8 + ct) * 64 + lane) << 3));
                acc[ct] = __builtin_amdgcn_mfma_f32_16x16x32_bf16(af, bfv, acc[ct], 0, 0, 0);
            }
        }
        float g0 = gf[r0 + quad * 4 + 0];
        float g1 = gf[r0 + quad * 4 + 1];
        float g2 = gf[r0 + quad * 4 + 2];
        float g3 = gf[r0 + quad * 4 + 3];
        #pragma unroll
        for (int ct = 0; ct < 8; ct++) {
            int c = ct * 16 + m;
            float bl = blin[c];
            float gr[4] = {g0, g1, g2, g3};
            float ss = 0.f, qq = 0.f;
            #pragma unroll
            for (int reg = 0; reg < 4; reg++) {
                int r = r0 + quad * 4 + reg;
                float val = acc[ct][reg] + bl * gr[reg];
                out[(size_t)r * 128 + c] = val;
                ss += val; qq += val * val;
            }
            ss += __shfl_xor(ss, 16); qq += __shfl_xor(qq, 16);
            ss += __shfl_xor(ss, 32); qq += __shfl_xor(qq, 32);
            if (quad == 0) {
                atomicAdd(&ldsS[ct * 16 + m], ss);
                atomicAdd(&ldsQ[ct * 16 + m], qq);
            }
        }
    }
    __syncthreads();
    if (t < 128)        partials[(size_t)blockIdx.x * 256 + t] = ldsS[t];
    else                partials[(size_t)blockIdx.x * 256 + t] = ldsQ[t - 128];
}

// --- K7: parallel partials reduction: one wave per column ---
__global__ __launch_bounds__(64) void k_rstats(const float* __restrict__ partials,
                                               float* __restrict__ stats) {
    int c = blockIdx.x;          // 0..127
    int lane = threadIdx.x;      // 0..63
    float s = 0.f, q = 0.f;
    for (int b = lane; b < GEMM_BLOCKS; b += 64) {
        s += partials[(size_t)b * 256 + c];
        q += partials[(size_t)b * 256 + 128 + c];
    }
    #pragma unroll
    for (int off = 32; off; off >>= 1) {
        s += __shfl_down(s, off);
        q += __shfl_down(q, off);
    }
    if (lane == 0) {
        float mu = s * (1.f / N_V);
        float var = (q - s * mu) * (1.f / (N_V - 1));
        float sd = sqrtf(fmaxf(var, 0.f));
        stats[c] = mu;
        stats[128 + c] = 1.f / (sd + 1e-5f);
    }
}

// --- K8: normalize + ELU, in place, float4 ---
__global__ void k_finalize(float* __restrict__ out, const float* __restrict__ stats) {
    int i = blockIdx.x * blockDim.x + threadIdx.x;
    if (i >= N_V * 32) return;
    float4 v = ((float4*)out)[i];
    int c0 = (i * 4) & 127;
    float mu0 = stats[c0], mu1 = stats[c0 + 1], mu2 = stats[c0 + 2], mu3 = stats[c0 + 3];
    float is0 = stats[128 + c0], is1 = stats[128 + c0 + 1], is2 = stats[128 + c0 + 2], is3 = stats[128 + c0 + 3];
    v.x = (v.x - mu0) * is0; v.y = (v.y - mu1) * is1;
    v.z = (v.z - mu2) * is2; v.w = (v.w - mu3) * is3;
    v.x = v.x > 0.f ? v.x : expm1f(v.x);
    v.y = v.y > 0.f ? v.y : expm1f(v.y);
    v.z = v.z > 0.f ? v.z : expm1f(v.z);
    v.w = v.w > 0.f ? v.w : expm1f(v.w);
    ((float4*)out)[i] = v;
}

extern "C" void kernel_launch(void* const* d_in, const int* in_sizes, int n_in,
                              void* d_out, int out_size, void* d_ws, size_t ws_size,
                              hipStream_t stream) {
    const float* feat  = (const float*)d_in[0];
    const float* vtx   = (const float*)d_in[1];
    const int*   edges = (const int*)d_in[2];
    const int*   faces = (const int*)d_in[3];
    const float* W1   = (const float*)d_in[4];
    const float* b1   = (const float*)d_in[5];
    const float* W2   = (const float*)d_in[6];
    const float* b2   = (const float*)d_in[7];
    const float* Wlin = (const float*)d_in[8];
    const float* blin = (const float*)d_in[9];
    float* out = (float*)d_out;

    float* ws = (float*)d_ws;
    // Compacted layout via liveness aliasing — total 1,808,196 floats (7.23 MB),
    // below the round-2 proven-safe footprint (8.83 MB). Liveness:
    //   nrm [0..300000)           : k_face_normals .. k_edge
    //   cnt [300000..400000)      : k_count .. k_edge (cursor)
    //   row_start [400000..500001): k_scan3 .. k_agg
    //   partials (ALIAS ws[0..400128)): k_gemm .. k_rstats  (nrm/cnt/row_start dead)
    //   gf [500004..600004)       : k_agg .. k_gemm; reused as stats (k_rstats..)
    //   Wb [600004..608196)       : k_pack_w .. k_gemm
    //   csr_src [608196..1208196) : k_edge .. k_agg; eprefix ALIASES it (scan1..scan3)
    //   csr_w [1208196..1808196)  : k_edge .. k_agg; bsum ALIASES it (scan1..scan3)
    float* nrm        = ws;                              // 300000
    int*   cnt        = (int*)(ws + 300000);             // 100000 (cursor)
    int*   row_start  = (int*)(ws + 400000);             // 100001
    float* partials   = ws;                              // 400128 (alias, after row_start dead)
    float* gf         = ws + 500004;                     // 100000 (alias stats)
    unsigned short* Wb = (unsigned short*)(ws + 600004); // 16384 shorts (8192 floats)
    int*   csr_src    = (int*)(ws + 608196);             // 600000
    int*   eprefix    = csr_src;                         // alias (dead before csr_src written)
    float* csr_w      = ws + 1208196;                    // 600000
    int*   bsum       = (int*)csr_w;                     // alias (dead before csr_w written)
    float* stats      = gf;                              // alias (gf consumed by k_gemm)

    // zero nrm + cnt in one shot
    hipMemsetAsync(d_ws, 0, 400000 * sizeof(float), stream);

    k_count<<<(N_E + 255) / 256, 256, 0, stream>>>(edges, cnt);
    k_face_normals<<<(N_F + 255) / 256, 256, 0, stream>>>(vtx, faces, nrm);
    k_norm_normals<<<(N_V + 255) / 256, 256, 0, stream>>>(nrm);
    k_scan1<<<SCAN_BLOCKS, 1024, 0, stream>>>(cnt, eprefix, bsum);
    k_scan2<<<1, 128, 0, stream>>>(bsum);
    k_scan3<<<(N_V + 255) / 256, 256, 0, stream>>>(eprefix, bsum, row_start, cnt);
    k_pack_w<<<64, 256, 0, stream>>>(Wlin, Wb);
    k_edge<<<(N_E + 255) / 256, 256, 0, stream>>>(vtx, edges, nrm, W1, b1, W2, b2,
                                                  cnt, csr_src, csr_w);
    k_agg<<<N_V / 4, 256, 0, stream>>>(feat, row_start, csr_src, csr_w, out, gf);
    k_gemm<<<GEMM_BLOCKS, 256, 0, stream>>>(out, gf, Wb, blin, partials);
    k_rstats<<<128, 64, 0, stream>>>(partials, stats);
    k_finalize<<<(N_V * 32 + 255) / 256, 256, 0, stream>>>(out, stats);
}

// Round 5
// 329.275 us; speedup vs baseline: 2.0131x; 1.2830x over previous
//
#include <hip/hip_runtime.h>
#include <hip/hip_bf16.h>
#include <math.h>

#define N_V 100000
#define N_E 600000
#define N_F 200000
// CIN = COUT = 128, H = 32

typedef __attribute__((ext_vector_type(8))) short bf16x8;
typedef __attribute__((ext_vector_type(4))) float f32x4;

#define GEMM_WAVES (N_V / 16)               // 6250
#define GEMM_BLOCKS ((GEMM_WAVES + 3) / 4)  // 1563
#define FACE_BLOCKS 782                     // ceil(200000/256)
#define EDGE_BLOCKS 2344                    // ceil(600000/256)
#define PACK_BLOCKS 64

__device__ __forceinline__ unsigned short f2bf(float f) {
    unsigned int u = __builtin_bit_cast(unsigned int, f);
    u += 0x7fffu + ((u >> 16) & 1u);   // round-to-nearest-even
    return (unsigned short)(u >> 16);
}

// --- K1: fused build — linked-list push for face corners + edges, + Wlin pack.
// One atomicExch per element; no count/scan/cursor passes.
__global__ void k_build(const int* __restrict__ edges, const int* __restrict__ faces,
                        const float* __restrict__ Wlin,
                        int* __restrict__ head_e, int* __restrict__ next_e,
                        int* __restrict__ head_f, int* __restrict__ next_f,
                        unsigned short* __restrict__ Wb) {
    int b = blockIdx.x;
    int t = threadIdx.x;
    if (b < FACE_BLOCKS) {
        int f = b * 256 + t;
        if (f < N_F) {
            #pragma unroll
            for (int j = 0; j < 3; j++) {
                int v = faces[j * N_F + f];
                int c = 3 * f + j;                 // unique corner id
                int old = atomicExch(&head_f[v], c);
                next_f[c] = old;
            }
        }
    } else if (b < FACE_BLOCKS + EDGE_BLOCKS) {
        int e = (b - FACE_BLOCKS) * 256 + t;
        if (e < N_E) {
            int d = edges[N_E + e];
            int old = atomicExch(&head_e[d], e);
            next_e[e] = old;
        }
    } else {
        // pack Wlin (fp32 [128,128]) into bf16 MFMA B-fragment order
        int i = (b - FACE_BLOCKS - EDGE_BLOCKS) * 256 + t;   // 0..16383
        int j = i & 7;
        int lane = (i >> 3) & 63;
        int ct = (i >> 9) & 7;
        int kk = i >> 12;
        int k = kk * 32 + (lane >> 4) * 8 + j;
        int n = ct * 16 + (lane & 15);
        Wb[i] = f2bf(Wlin[k * 128 + n]);
    }
}

// --- K2: vertex normals via face-list walk; recompute face normal per hop ---
__global__ void k_vnorm(const float* __restrict__ vtx, const int* __restrict__ faces,
                        const int* __restrict__ head_f, const int* __restrict__ next_f,
                        float* __restrict__ nrm) {
    int v = blockIdx.x * 256 + threadIdx.x;
    if (v >= N_V) return;
    float nx = 0.f, ny = 0.f, nz = 0.f;
    int c = head_f[v];
    while (c >= 0) {
        int f = c / 3;
        int i0 = faces[f], i1 = faces[N_F + f], i2 = faces[2 * N_F + f];
        float ax = vtx[3 * i0], ay = vtx[3 * i0 + 1], az = vtx[3 * i0 + 2];
        float bx = vtx[3 * i1] - ax, by = vtx[3 * i1 + 1] - ay, bz = vtx[3 * i1 + 2] - az;
        float cx = vtx[3 * i2] - ax, cy = vtx[3 * i2 + 1] - ay, cz = vtx[3 * i2 + 2] - az;
        nx += by * cz - bz * cy;
        ny += bz * cx - bx * cz;
        nz += bx * cy - by * cx;
        c = next_f[c];
    }
    float inv = 1.f / (sqrtf(nx * nx + ny * ny + nz * nz) + 1e-8f);
    nrm[3 * v] = nx * inv; nrm[3 * v + 1] = ny * inv; nrm[3 * v + 2] = nz * inv;
}

// --- K3: per-edge MLP -> w (streamed edge-major write, no atomics) ---
__global__ void k_edge(const float* __restrict__ vtx, const int* __restrict__ edges,
                       const float* __restrict__ nrm,
                       const float* __restrict__ W1, const float* __restrict__ b1,
                       const float* __restrict__ W2, const float* __restrict__ b2,
                       float* __restrict__ wbuf) {
    __shared__ float sW1[96], sb1[32], sW2[192], sb2[6];
    int t = threadIdx.x;
    if (t < 96)  sW1[t] = W1[t];
    if (t < 32)  sb1[t] = b1[t];
    if (t < 192) sW2[t] = W2[t];
    if (t < 6)   sb2[t] = b2[t];
    __syncthreads();
    int e = blockIdx.x * blockDim.x + t;
    if (e >= N_E) return;
    int s = edges[e], d = edges[N_E + e];
    float dx = vtx[3 * d] - vtx[3 * s];
    float dy = vtx[3 * d + 1] - vtx[3 * s + 1];
    float dz = vtx[3 * d + 2] - vtx[3 * s + 2];
    float nx = nrm[3 * s], ny = nrm[3 * s + 1], nz = nrm[3 * s + 2];
    float dp = dx * nx + dy * ny + dz * nz;
    float tx = dx - dp * nx, ty = dy - dp * ny, tz = dz - dp * nz;
    float th0 = sb2[0], th1 = sb2[1], th2 = sb2[2], th3 = sb2[3], th4 = sb2[4], th5 = sb2[5];
    #pragma unroll
    for (int j = 0; j < 32; j++) {
        float h = tx * sW1[j] + ty * sW1[32 + j] + tz * sW1[64 + j] + sb1[j];
        h = fmaxf(h, 0.f);
        const float* w2r = &sW2[j * 6];
        th0 += h * w2r[0]; th1 += h * w2r[1]; th2 += h * w2r[2];
        th3 += h * w2r[3]; th4 += h * w2r[4]; th5 += h * w2r[5];
    }
    // S symmetric; q = ||S t||^2
    float ux = th0 * tx + th1 * ty + th2 * tz;
    float uy = th1 * tx + th3 * ty + th4 * tz;
    float uz = th2 * tx + th4 * ty + th5 * tz;
    float q = ux * ux + uy * uy + uz * uz;
    wbuf[e] = expf(-q);
}

// --- K4: aggregate via edge-list walk. Half-wave (32 lanes x float4) per vertex. ---
__global__ __launch_bounds__(256) void k_agg(const float* __restrict__ feat,
                                             const int* __restrict__ edges,
                                             const int* __restrict__ head_e,
                                             const int* __restrict__ next_e,
                                             const float* __restrict__ wbuf,
                                             float* __restrict__ out,
                                             float* __restrict__ gf) {
    int v = blockIdx.x * 8 + (threadIdx.x >> 5);
    if (v >= N_V) return;
    int lane = threadIdx.x & 31;
    float4 acc = {0.f, 0.f, 0.f, 0.f};
    float den = 0.f;
    int e = head_e[v];
    while (e >= 0) {
        int s = edges[e];
        float w = wbuf[e];
        float4 f = *(const float4*)(feat + (size_t)s * 128 + 4 * lane);
        acc.x += w * f.x; acc.y += w * f.y; acc.z += w * f.z; acc.w += w * f.w;
        den += w;
        e = next_e[e];
    }
    float inv = 1.f / (den + 1e-5f);
    acc.x *= inv; acc.y *= inv; acc.z *= inv; acc.w *= inv;
    *(float4*)(out + (size_t)v * 128 + 4 * lane) = acc;
    if (lane == 0) gf[v] = den * inv;
}

// --- K5: in-place GEMM out = A @ Wlin + blin*gf, fused column-stats partials ---
__global__ __launch_bounds__(256) void k_gemm(float* __restrict__ out,
                                              const float* __restrict__ gf,
                                              const unsigned short* __restrict__ Wb,
                                              const float* __restrict__ blin,
                                              float* __restrict__ partials) {
    __shared__ float ldsS[128], ldsQ[128];
    int t = threadIdx.x;
    if (t < 128) { ldsS[t] = 0.f; ldsQ[t] = 0.f; }
    __syncthreads();

    int wave = (blockIdx.x * 256 + t) >> 6;
    int lane = t & 63;
    int m = lane & 15, quad = lane >> 4;
    if (wave < GEMM_WAVES) {
        int r0 = wave * 16;
        const float* arow = out + (size_t)(r0 + m) * 128;
        f32x4 acc[8];
        #pragma unroll
        for (int ct = 0; ct < 8; ct++) acc[ct] = (f32x4){0.f, 0.f, 0.f, 0.f};
        #pragma unroll
        for (int kk = 0; kk < 4; kk++) {
            int k0 = kk * 32 + quad * 8;
            float4 a0 = *(const float4*)(arow + k0);
            float4 a1 = *(const float4*)(arow + k0 + 4);
            bf16x8 af;
            af[0] = (short)f2bf(a0.x); af[1] = (short)f2bf(a0.y);
            af[2] = (short)f2bf(a0.z); af[3] = (short)f2bf(a0.w);
            af[4] = (short)f2bf(a1.x); af[5] = (short)f2bf(a1.y);
            af[6] = (short)f2bf(a1.z); af[7] = (short)f2bf(a1.w);
            #pragma unroll
            for (int ct = 0; ct < 8; ct++) {
                bf16x8 bfv = *(const bf16x8*)(Wb + (((kk * 8 + ct) * 64 + lane) << 3));
                acc[ct] = __builtin_amdgcn_mfma_f32_16x16x32_bf16(af, bfv, acc[ct], 0, 0, 0);
            }
        }
        float g0 = gf[r0 + quad * 4 + 0];
        float g1 = gf[r0 + quad * 4 + 1];
        float g2 = gf[r0 + quad * 4 + 2];
        float g3 = gf[r0 + quad * 4 + 3];
        #pragma unroll
        for (int ct = 0; ct < 8; ct++) {
            int c = ct * 16 + m;
            float bl = blin[c];
            float gr[4] = {g0, g1, g2, g3};
            float ss = 0.f, qq = 0.f;
            #pragma unroll
            for (int reg = 0; reg < 4; reg++) {
                int r = r0 + quad * 4 + reg;
                float val = acc[ct][reg] + bl * gr[reg];
                out[(size_t)r * 128 + c] = val;
                ss += val; qq += val * val;
            }
            ss += __shfl_xor(ss, 16); qq += __shfl_xor(qq, 16);
            ss += __shfl_xor(ss, 32); qq += __shfl_xor(qq, 32);
            if (quad == 0) {
                atomicAdd(&ldsS[ct * 16 + m], ss);
                atomicAdd(&ldsQ[ct * 16 + m], qq);
            }
        }
    }
    __syncthreads();
    if (t < 128)        partials[(size_t)blockIdx.x * 256 + t] = ldsS[t];
    else                partials[(size_t)blockIdx.x * 256 + t] = ldsQ[t - 128];
}

// --- K6: parallel partials reduction: one wave per column ---
__global__ __launch_bounds__(64) void k_rstats(const float* __restrict__ partials,
                                               float* __restrict__ stats) {
    int c = blockIdx.x;          // 0..127
    int lane = threadIdx.x;      // 0..63
    float s = 0.f, q = 0.f;
    for (int b = lane; b < GEMM_BLOCKS; b += 64) {
        s += partials[(size_t)b * 256 + c];
        q += partials[(size_t)b * 256 + 128 + c];
    }
    #pragma unroll
    for (int off = 32; off; off >>= 1) {
        s += __shfl_down(s, off);
        q += __shfl_down(q, off);
    }
    if (lane == 0) {
        float mu = s * (1.f / N_V);
        float var = (q - s * mu) * (1.f / (N_V - 1));
        float sd = sqrtf(fmaxf(var, 0.f));
        stats[c] = mu;
        stats[128 + c] = 1.f / (sd + 1e-5f);
    }
}

// --- K7: normalize + ELU, in place, float4 ---
__global__ void k_finalize(float* __restrict__ out, const float* __restrict__ stats) {
    int i = blockIdx.x * blockDim.x + threadIdx.x;
    if (i >= N_V * 32) return;
    float4 v = ((float4*)out)[i];
    int c0 = (i * 4) & 127;
    float mu0 = stats[c0], mu1 = stats[c0 + 1], mu2 = stats[c0 + 2], mu3 = stats[c0 + 3];
    float is0 = stats[128 + c0], is1 = stats[128 + c0 + 1], is2 = stats[128 + c0 + 2], is3 = stats[128 + c0 + 3];
    v.x = (v.x - mu0) * is0; v.y = (v.y - mu1) * is1;
    v.z = (v.z - mu2) * is2; v.w = (v.w - mu3) * is3;
    v.x = v.x > 0.f ? v.x : expm1f(v.x);
    v.y = v.y > 0.f ? v.y : expm1f(v.y);
    v.z = v.z > 0.f ? v.z : expm1f(v.z);
    v.w = v.w > 0.f ? v.w : expm1f(v.w);
    ((float4*)out)[i] = v;
}

extern "C" void kernel_launch(void* const* d_in, const int* in_sizes, int n_in,
                              void* d_out, int out_size, void* d_ws, size_t ws_size,
                              hipStream_t stream) {
    const float* feat  = (const float*)d_in[0];
    const float* vtx   = (const float*)d_in[1];
    const int*   edges = (const int*)d_in[2];
    const int*   faces = (const int*)d_in[3];
    const float* W1   = (const float*)d_in[4];
    const float* b1   = (const float*)d_in[5];
    const float* W2   = (const float*)d_in[6];
    const float* b2   = (const float*)d_in[7];
    const float* Wlin = (const float*)d_in[8];
    const float* blin = (const float*)d_in[9];
    float* out = (float*)d_out;

    float* ws = (float*)d_ws;
    // Workspace: peak 1,808,192 floats (7.23 MB) < proven-safe 8.83 MB. Liveness:
    //   head_e [0..100000)        : k_build .. k_agg
    //   head_f [100000..200000)   : k_build .. k_vnorm
    //   nrm    [200000..500000)   : k_vnorm .. k_edge
    //   gf     [500000..600000)   : k_agg .. k_gemm; reused as stats (k_rstats..)
    //   Wb     [600000..608192)   : k_build .. k_gemm
    //   next_e [608192..1208192)  : k_build .. k_agg; partials ALIASES it (k_gemm..k_rstats)
    //   next_f [1208192..1808192) : k_build .. k_vnorm; wbuf ALIASES it (k_edge..k_agg)
    int*   head_e = (int*)ws;                              // 100000
    int*   head_f = (int*)(ws + 100000);                   // 100000
    float* nrm    = ws + 200000;                           // 300000
    float* gf     = ws + 500000;                           // 100000
    unsigned short* Wb = (unsigned short*)(ws + 600000);   // 16384 shorts
    int*   next_e = (int*)(ws + 608192);                   // 600000
    float* partials = ws + 608192;                         // 400128 (alias, next_e dead)
    int*   next_f = (int*)(ws + 1208192);                  // 600000
    float* wbuf   = ws + 1208192;                          // 600000 (alias, next_f dead)
    float* stats  = gf;                                    // alias (gf consumed by k_gemm)

    // init both head arrays to -1
    hipMemsetAsync(d_ws, 0xFF, 200000 * sizeof(int), stream);

    k_build<<<FACE_BLOCKS + EDGE_BLOCKS + PACK_BLOCKS, 256, 0, stream>>>(
        edges, faces, Wlin, head_e, next_e, head_f, next_f, Wb);
    k_vnorm<<<(N_V + 255) / 256, 256, 0, stream>>>(vtx, faces, head_f, next_f, nrm);
    k_edge<<<EDGE_BLOCKS, 256, 0, stream>>>(vtx, edges, nrm, W1, b1, W2, b2, wbuf);
    k_agg<<<N_V / 8, 256, 0, stream>>>(feat, edges, head_e, next_e, wbuf, out, gf);
    k_gemm<<<GEMM_BLOCKS, 256, 0, stream>>>(out, gf, Wb, blin, partials);
    k_rstats<<<128, 64, 0, stream>>>(partials, stats);
    k_finalize<<<(N_V * 32 + 255) / 256, 256, 0, stream>>>(out, stats);
}

// Round 6
// 311.081 us; speedup vs baseline: 2.1309x; 1.0585x over previous
//
#include <hip/hip_runtime.h>
#include <hip/hip_bf16.h>
#include <math.h>

#define N_V 100000
#define N_E 600000
#define N_F 200000
// CIN = COUT = 128, H = 32

typedef __attribute__((ext_vector_type(8))) short bf16x8;
typedef __attribute__((ext_vector_type(4))) float f32x4;

#define FUSED_BLOCKS 1563                   // ceil(100000/64); 64 rows per block
#define FACE_BLOCKS 782                     // ceil(200000/256)
#define EDGE_BLOCKS 2344                    // ceil(600000/256)
#define PACK_BLOCKS 64

__device__ __forceinline__ unsigned short f2bf(float f) {
    unsigned int u = __builtin_bit_cast(unsigned int, f);
    u += 0x7fffu + ((u >> 16) & 1u);   // round-to-nearest-even
    return (unsigned short)(u >> 16);
}

// --- K1: fused build — linked-list push for face corners + edges, + Wlin pack ---
__global__ void k_build(const int* __restrict__ edges, const int* __restrict__ faces,
                        const float* __restrict__ Wlin,
                        int* __restrict__ head_e, int* __restrict__ next_e,
                        int* __restrict__ head_f, int* __restrict__ next_f,
                        unsigned short* __restrict__ Wb) {
    int b = blockIdx.x;
    int t = threadIdx.x;
    if (b < FACE_BLOCKS) {
        int f = b * 256 + t;
        if (f < N_F) {
            #pragma unroll
            for (int j = 0; j < 3; j++) {
                int v = faces[j * N_F + f];
                int c = 3 * f + j;                 // unique corner id
                int old = atomicExch(&head_f[v], c);
                next_f[c] = old;
            }
        }
    } else if (b < FACE_BLOCKS + EDGE_BLOCKS) {
        int e = (b - FACE_BLOCKS) * 256 + t;
        if (e < N_E) {
            int d = edges[N_E + e];
            int old = atomicExch(&head_e[d], e);
            next_e[e] = old;
        }
    } else {
        // pack Wlin (fp32 [128,128]) into bf16 MFMA B-fragment order
        int i = (b - FACE_BLOCKS - EDGE_BLOCKS) * 256 + t;   // 0..16383
        int j = i & 7;
        int lane = (i >> 3) & 63;
        int ct = (i >> 9) & 7;
        int kk = i >> 12;
        int k = kk * 32 + (lane >> 4) * 8 + j;
        int n = ct * 16 + (lane & 15);
        Wb[i] = f2bf(Wlin[k * 128 + n]);
    }
}

// --- K2: vertex normals via face-list walk; recompute face normal per hop ---
__global__ void k_vnorm(const float* __restrict__ vtx, const int* __restrict__ faces,
                        const int* __restrict__ head_f, const int* __restrict__ next_f,
                        float* __restrict__ nrm) {
    int v = blockIdx.x * 256 + threadIdx.x;
    if (v >= N_V) return;
    float nx = 0.f, ny = 0.f, nz = 0.f;
    int c = head_f[v];
    while (c >= 0) {
        int f = c / 3;
        int i0 = faces[f], i1 = faces[N_F + f], i2 = faces[2 * N_F + f];
        float ax = vtx[3 * i0], ay = vtx[3 * i0 + 1], az = vtx[3 * i0 + 2];
        float bx = vtx[3 * i1] - ax, by = vtx[3 * i1 + 1] - ay, bz = vtx[3 * i1 + 2] - az;
        float cx = vtx[3 * i2] - ax, cy = vtx[3 * i2 + 1] - ay, cz = vtx[3 * i2 + 2] - az;
        nx += by * cz - bz * cy;
        ny += bz * cx - bx * cz;
        nz += bx * cy - by * cx;
        c = next_f[c];
    }
    float inv = 1.f / (sqrtf(nx * nx + ny * ny + nz * nz) + 1e-8f);
    nrm[3 * v] = nx * inv; nrm[3 * v + 1] = ny * inv; nrm[3 * v + 2] = nz * inv;
}

// --- K3: per-edge MLP -> w (streamed write, no atomics) ---
__global__ void k_edge(const float* __restrict__ vtx, const int* __restrict__ edges,
                       const float* __restrict__ nrm,
                       const float* __restrict__ W1, const float* __restrict__ b1,
                       const float* __restrict__ W2, const float* __restrict__ b2,
                       float* __restrict__ wbuf) {
    __shared__ float sW1[96], sb1[32], sW2[192], sb2[6];
    int t = threadIdx.x;
    if (t < 96)  sW1[t] = W1[t];
    if (t < 32)  sb1[t] = b1[t];
    if (t < 192) sW2[t] = W2[t];
    if (t < 6)   sb2[t] = b2[t];
    __syncthreads();
    int e = blockIdx.x * blockDim.x + t;
    if (e >= N_E) return;
    int s = edges[e], d = edges[N_E + e];
    float dx = vtx[3 * d] - vtx[3 * s];
    float dy = vtx[3 * d + 1] - vtx[3 * s + 1];
    float dz = vtx[3 * d + 2] - vtx[3 * s + 2];
    float nx = nrm[3 * s], ny = nrm[3 * s + 1], nz = nrm[3 * s + 2];
    float dp = dx * nx + dy * ny + dz * nz;
    float tx = dx - dp * nx, ty = dy - dp * ny, tz = dz - dp * nz;
    float th0 = sb2[0], th1 = sb2[1], th2 = sb2[2], th3 = sb2[3], th4 = sb2[4], th5 = sb2[5];
    #pragma unroll
    for (int j = 0; j < 32; j++) {
        float h = tx * sW1[j] + ty * sW1[32 + j] + tz * sW1[64 + j] + sb1[j];
        h = fmaxf(h, 0.f);
        const float* w2r = &sW2[j * 6];
        th0 += h * w2r[0]; th1 += h * w2r[1]; th2 += h * w2r[2];
        th3 += h * w2r[3]; th4 += h * w2r[4]; th5 += h * w2r[5];
    }
    // S symmetric; q = ||S t||^2
    float ux = th0 * tx + th1 * ty + th2 * tz;
    float uy = th1 * tx + th3 * ty + th4 * tz;
    float uz = th2 * tx + th4 * ty + th5 * tz;
    float q = ux * ux + uy * uy + uz * uz;
    wbuf[e] = expf(-q);
}

// --- K4: FUSED aggregate + GEMM + bias + stats partials.
// 512 threads (8 waves) per block, 64 vertices per block.
// Phase 1: 16 half-waves walk edge chains, deposit bf16 A-rows in LDS (stride 136).
// Phase 2: wave w owns column tile ct=w: 4 row-tiles x 4 MFMAs from LDS A.
__global__ __launch_bounds__(512) void k_fused(const float* __restrict__ feat,
                                               const int* __restrict__ edges,
                                               const int* __restrict__ head_e,
                                               const int* __restrict__ next_e,
                                               const float* __restrict__ wbuf,
                                               const unsigned short* __restrict__ Wb,
                                               const float* __restrict__ blin,
                                               float* __restrict__ out,
                                               float* __restrict__ partials) {
    __shared__ __align__(16) unsigned short At[64 * 136];   // 17408 B, +8 pad breaks bank conflicts
    __shared__ float gs[64];
    int t = threadIdx.x;
    int hw = t >> 5;            // half-wave id 0..15
    int hl = t & 31;            // lane in half-wave

    // Phase 1: aggregate 64 rows (4 reps x 16 half-waves)
    #pragma unroll
    for (int rep = 0; rep < 4; rep++) {
        int row = rep * 16 + hw;
        int v = blockIdx.x * 64 + row;
        float4 acc = {0.f, 0.f, 0.f, 0.f};
        float den = 0.f;
        if (v < N_V) {
            int e = head_e[v];
            while (e >= 0) {
                int s = edges[e];
                float w = wbuf[e];
                float4 f = *(const float4*)(feat + (size_t)s * 128 + 4 * hl);
                acc.x += w * f.x; acc.y += w * f.y; acc.z += w * f.z; acc.w += w * f.w;
                den += w;
                e = next_e[e];
            }
        }
        float inv = 1.f / (den + 1e-5f);
        ushort4 p;
        p.x = f2bf(acc.x * inv); p.y = f2bf(acc.y * inv);
        p.z = f2bf(acc.z * inv); p.w = f2bf(acc.w * inv);
        *(ushort4*)(&At[row * 136 + 4 * hl]) = p;
        if (hl == 0) gs[row] = den * inv;
    }
    __syncthreads();

    // Phase 2: MFMA. wave id = column tile ct.
    int ct = t >> 6;
    int lane = t & 63;
    int m = lane & 15, quad = lane >> 4;
    bf16x8 bfr[4];
    #pragma unroll
    for (int kk = 0; kk < 4; kk++)
        bfr[kk] = *(const bf16x8*)(Wb + (((kk * 8 + ct) * 64 + lane) << 3));
    float bl = blin[ct * 16 + m];
    float ssr = 0.f, qqr = 0.f;
    #pragma unroll
    for (int tile = 0; tile < 4; tile++) {
        f32x4 acc = (f32x4){0.f, 0.f, 0.f, 0.f};
        #pragma unroll
        for (int kk = 0; kk < 4; kk++) {
            bf16x8 af = *(const bf16x8*)(&At[(tile * 16 + m) * 136 + kk * 32 + quad * 8]);
            acc = __builtin_amdgcn_mfma_f32_16x16x32_bf16(af, bfr[kk], acc, 0, 0, 0);
        }
        int r0 = blockIdx.x * 64 + tile * 16;
        #pragma unroll
        for (int reg = 0; reg < 4; reg++) {
            int r = r0 + quad * 4 + reg;
            float g = gs[tile * 16 + quad * 4 + reg];
            float val = acc[reg] + bl * g;
            if (r < N_V) out[(size_t)r * 128 + ct * 16 + m] = val;
            ssr += val; qqr += val * val;   // invalid rows contribute exactly 0
        }
    }
    // reduce over quads (rows) -> per-column sums; each column owned by one wave
    ssr += __shfl_xor(ssr, 16); qqr += __shfl_xor(qqr, 16);
    ssr += __shfl_xor(ssr, 32); qqr += __shfl_xor(qqr, 32);
    if (quad == 0) {
        partials[(size_t)blockIdx.x * 256 + ct * 16 + m] = ssr;
        partials[(size_t)blockIdx.x * 256 + 128 + ct * 16 + m] = qqr;
    }
}

// --- K5: parallel partials reduction: one wave per column ---
__global__ __launch_bounds__(64) void k_rstats(const float* __restrict__ partials,
                                               float* __restrict__ stats) {
    int c = blockIdx.x;          // 0..127
    int lane = threadIdx.x;      // 0..63
    float s = 0.f, q = 0.f;
    for (int b = lane; b < FUSED_BLOCKS; b += 64) {
        s += partials[(size_t)b * 256 + c];
        q += partials[(size_t)b * 256 + 128 + c];
    }
    #pragma unroll
    for (int off = 32; off; off >>= 1) {
        s += __shfl_down(s, off);
        q += __shfl_down(q, off);
    }
    if (lane == 0) {
        float mu = s * (1.f / N_V);
        float var = (q - s * mu) * (1.f / (N_V - 1));
        float sd = sqrtf(fmaxf(var, 0.f));
        stats[c] = mu;
        stats[128 + c] = 1.f / (sd + 1e-5f);
    }
}

// --- K6: normalize + ELU, in place, float4 ---
__global__ void k_finalize(float* __restrict__ out, const float* __restrict__ stats) {
    int i = blockIdx.x * blockDim.x + threadIdx.x;
    if (i >= N_V * 32) return;
    float4 v = ((float4*)out)[i];
    int c0 = (i * 4) & 127;
    float mu0 = stats[c0], mu1 = stats[c0 + 1], mu2 = stats[c0 + 2], mu3 = stats[c0 + 3];
    float is0 = stats[128 + c0], is1 = stats[128 + c0 + 1], is2 = stats[128 + c0 + 2], is3 = stats[128 + c0 + 3];
    v.x = (v.x - mu0) * is0; v.y = (v.y - mu1) * is1;
    v.z = (v.z - mu2) * is2; v.w = (v.w - mu3) * is3;
    v.x = v.x > 0.f ? v.x : expm1f(v.x);
    v.y = v.y > 0.f ? v.y : expm1f(v.y);
    v.z = v.z > 0.f ? v.z : expm1f(v.z);
    v.w = v.w > 0.f ? v.w : expm1f(v.w);
    ((float4*)out)[i] = v;
}

extern "C" void kernel_launch(void* const* d_in, const int* in_sizes, int n_in,
                              void* d_out, int out_size, void* d_ws, size_t ws_size,
                              hipStream_t stream) {
    const float* feat  = (const float*)d_in[0];
    const float* vtx   = (const float*)d_in[1];
    const int*   edges = (const int*)d_in[2];
    const int*   faces = (const int*)d_in[3];
    const float* W1   = (const float*)d_in[4];
    const float* b1   = (const float*)d_in[5];
    const float* W2   = (const float*)d_in[6];
    const float* b2   = (const float*)d_in[7];
    const float* Wlin = (const float*)d_in[8];
    const float* blin = (const float*)d_in[9];
    float* out = (float*)d_out;

    float* ws = (float*)d_ws;
    // Workspace: peak 1,708,320 floats (6.83 MB) < proven-safe 8.83 MB. Liveness:
    //   head_e   [0..100000)          : k_build .. k_fused; stats ALIASES [0..256) (k_rstats..)
    //   head_f   [100000..200000)     : k_build .. k_vnorm
    //   nrm      [200000..500000)     : k_vnorm .. k_edge
    //   partials [100000..500128)     : ALIAS head_f+nrm(+128) — k_fused .. k_rstats
    //   next_e   [500128..1100128)    : k_build .. k_fused
    //   next_f   [1100128..1700128)   : k_build .. k_vnorm; wbuf ALIASES it (k_edge..k_fused)
    //   Wb       [1700128..1708320)   : k_build .. k_fused (16384 shorts)
    int*   head_e   = (int*)ws;                              // 100000
    int*   head_f   = (int*)(ws + 100000);                   // 100000
    float* nrm      = ws + 200000;                           // 300000
    float* partials = ws + 100000;                           // 400128 (alias)
    int*   next_e   = (int*)(ws + 500128);                   // 600000
    int*   next_f   = (int*)(ws + 1100128);                  // 600000
    float* wbuf     = ws + 1100128;                          // 600000 (alias, next_f dead)
    unsigned short* Wb = (unsigned short*)(ws + 1700128);    // 16384 shorts
    float* stats    = ws;                                    // 256 (alias, head_e dead)

    // init both head arrays to -1
    hipMemsetAsync(d_ws, 0xFF, 200000 * sizeof(int), stream);

    k_build<<<FACE_BLOCKS + EDGE_BLOCKS + PACK_BLOCKS, 256, 0, stream>>>(
        edges, faces, Wlin, head_e, next_e, head_f, next_f, Wb);
    k_vnorm<<<(N_V + 255) / 256, 256, 0, stream>>>(vtx, faces, head_f, next_f, nrm);
    k_edge<<<EDGE_BLOCKS, 256, 0, stream>>>(vtx, edges, nrm, W1, b1, W2, b2, wbuf);
    k_fused<<<FUSED_BLOCKS, 512, 0, stream>>>(feat, edges, head_e, next_e, wbuf,
                                              Wb, blin, out, partials);
    k_rstats<<<128, 64, 0, stream>>>(partials, stats);
    k_finalize<<<(N_V * 32 + 255) / 256, 256, 0, stream>>>(out, stats);
}

// Round 7
// 289.557 us; speedup vs baseline: 2.2893x; 1.0743x over previous
//
#include <hip/hip_runtime.h>
#include <hip/hip_bf16.h>
#include <math.h>

#define N_V 100000
#define N_E 600000
#define N_F 200000
// CIN = COUT = 128, H = 32

typedef __attribute__((ext_vector_type(8))) short bf16x8;
typedef __attribute__((ext_vector_type(4))) float f32x4;

#define FUSED_BLOCKS 1563                   // ceil(100000/64); 64 rows per block
#define FACE_BLOCKS 782                     // ceil(200000/256)
#define EDGE_BLOCKS 2344                    // ceil(600000/256)
#define PACK_BLOCKS 64

__device__ __forceinline__ unsigned short f2bf(float f) {
    unsigned int u = __builtin_bit_cast(unsigned int, f);
    u += 0x7fffu + ((u >> 16) & 1u);   // round-to-nearest-even
    return (unsigned short)(u >> 16);
}

// --- K1: per-face normals (streamed) + corner linked-list push + Wlin pack ---
__global__ void k_fn(const float* __restrict__ vtx, const int* __restrict__ faces,
                     const float* __restrict__ Wlin,
                     float* __restrict__ fnbuf,
                     int* __restrict__ head_f, int* __restrict__ next_f,
                     unsigned short* __restrict__ Wb) {
    int b = blockIdx.x;
    int t = threadIdx.x;
    if (b < FACE_BLOCKS) {
        int f = b * 256 + t;
        if (f >= N_F) return;
        int i0 = faces[f], i1 = faces[N_F + f], i2 = faces[2 * N_F + f];
        // push corners first so the exch latency overlaps the vtx gathers
        #pragma unroll
        for (int j = 0; j < 3; j++) {
            int v = (j == 0) ? i0 : (j == 1 ? i1 : i2);
            int c = 3 * f + j;
            int old = atomicExch(&head_f[v], c);
            next_f[c] = old;
        }
        float ax = vtx[3 * i0], ay = vtx[3 * i0 + 1], az = vtx[3 * i0 + 2];
        float bx = vtx[3 * i1] - ax, by = vtx[3 * i1 + 1] - ay, bz = vtx[3 * i1 + 2] - az;
        float cx = vtx[3 * i2] - ax, cy = vtx[3 * i2 + 1] - ay, cz = vtx[3 * i2 + 2] - az;
        fnbuf[f]           = by * cz - bz * cy;
        fnbuf[N_F + f]     = bz * cx - bx * cz;
        fnbuf[2 * N_F + f] = bx * cy - by * cx;
    } else {
        // pack Wlin (fp32 [128,128]) into bf16 MFMA B-fragment order
        int i = (b - FACE_BLOCKS) * 256 + t;   // 0..16383
        int j = i & 7;
        int lane = (i >> 3) & 63;
        int ct = (i >> 9) & 7;
        int kk = i >> 12;
        int k = kk * 32 + (lane >> 4) * 8 + j;
        int n = ct * 16 + (lane & 15);
        Wb[i] = f2bf(Wlin[k * 128 + n]);
    }
}

// --- K2: vertex normals via corner-list walk over cached fnbuf ---
__global__ void k_vnorm(const float* __restrict__ fnbuf,
                        const int* __restrict__ head_f, const int* __restrict__ next_f,
                        float* __restrict__ nrm) {
    int v = blockIdx.x * 256 + threadIdx.x;
    if (v >= N_V) return;
    float nx = 0.f, ny = 0.f, nz = 0.f;
    int c = head_f[v];
    while (c >= 0) {
        int f = (unsigned)c / 3u;
        nx += fnbuf[f];
        ny += fnbuf[N_F + f];
        nz += fnbuf[2 * N_F + f];
        c = next_f[c];
    }
    float inv = 1.f / (sqrtf(nx * nx + ny * ny + nz * nz) + 1e-8f);
    nrm[3 * v] = nx * inv; nrm[3 * v + 1] = ny * inv; nrm[3 * v + 2] = nz * inv;
}

// --- K3: per-edge MLP -> w; fused dst linked-list push (exch hides under MLP) ---
__global__ void k_edge(const float* __restrict__ vtx, const int* __restrict__ edges,
                       const float* __restrict__ nrm,
                       const float* __restrict__ W1, const float* __restrict__ b1,
                       const float* __restrict__ W2, const float* __restrict__ b2,
                       float* __restrict__ wbuf,
                       int* __restrict__ head_e, int* __restrict__ next_e) {
    __shared__ float sW1[96], sb1[32], sW2[192], sb2[6];
    int t = threadIdx.x;
    if (t < 96)  sW1[t] = W1[t];
    if (t < 32)  sb1[t] = b1[t];
    if (t < 192) sW2[t] = W2[t];
    if (t < 6)   sb2[t] = b2[t];
    __syncthreads();
    int e = blockIdx.x * blockDim.x + t;
    if (e >= N_E) return;
    int s = edges[e], d = edges[N_E + e];
    int old = atomicExch(&head_e[d], e);      // issue early; latency hides under MLP
    float dx = vtx[3 * d] - vtx[3 * s];
    float dy = vtx[3 * d + 1] - vtx[3 * s + 1];
    float dz = vtx[3 * d + 2] - vtx[3 * s + 2];
    float nx = nrm[3 * s], ny = nrm[3 * s + 1], nz = nrm[3 * s + 2];
    float dp = dx * nx + dy * ny + dz * nz;
    float tx = dx - dp * nx, ty = dy - dp * ny, tz = dz - dp * nz;
    float th0 = sb2[0], th1 = sb2[1], th2 = sb2[2], th3 = sb2[3], th4 = sb2[4], th5 = sb2[5];
    #pragma unroll
    for (int j = 0; j < 32; j++) {
        float h = tx * sW1[j] + ty * sW1[32 + j] + tz * sW1[64 + j] + sb1[j];
        h = fmaxf(h, 0.f);
        const float* w2r = &sW2[j * 6];
        th0 += h * w2r[0]; th1 += h * w2r[1]; th2 += h * w2r[2];
        th3 += h * w2r[3]; th4 += h * w2r[4]; th5 += h * w2r[5];
    }
    // S symmetric; q = ||S t||^2
    float ux = th0 * tx + th1 * ty + th2 * tz;
    float uy = th1 * tx + th3 * ty + th4 * tz;
    float uz = th2 * tx + th4 * ty + th5 * tz;
    float q = ux * ux + uy * uy + uz * uz;
    next_e[e] = old;
    wbuf[e] = expf(-q);
}

// --- K4: FUSED aggregate + GEMM + bias + stats partials (as round 6) ---
__global__ __launch_bounds__(512) void k_fused(const float* __restrict__ feat,
                                               const int* __restrict__ edges,
                                               const int* __restrict__ head_e,
                                               const int* __restrict__ next_e,
                                               const float* __restrict__ wbuf,
                                               const unsigned short* __restrict__ Wb,
                                               const float* __restrict__ blin,
                                               float* __restrict__ out,
                                               float* __restrict__ partials) {
    __shared__ __align__(16) unsigned short At[64 * 136];
    __shared__ float gs[64];
    int t = threadIdx.x;
    int hw = t >> 5;            // half-wave id 0..15
    int hl = t & 31;            // lane in half-wave

    #pragma unroll
    for (int rep = 0; rep < 4; rep++) {
        int row = rep * 16 + hw;
        int v = blockIdx.x * 64 + row;
        float4 acc = {0.f, 0.f, 0.f, 0.f};
        float den = 0.f;
        if (v < N_V) {
            int e = head_e[v];
            while (e >= 0) {
                int s = edges[e];
                float w = wbuf[e];
                float4 f = *(const float4*)(feat + (size_t)s * 128 + 4 * hl);
                acc.x += w * f.x; acc.y += w * f.y; acc.z += w * f.z; acc.w += w * f.w;
                den += w;
                e = next_e[e];
            }
        }
        float inv = 1.f / (den + 1e-5f);
        ushort4 p;
        p.x = f2bf(acc.x * inv); p.y = f2bf(acc.y * inv);
        p.z = f2bf(acc.z * inv); p.w = f2bf(acc.w * inv);
        *(ushort4*)(&At[row * 136 + 4 * hl]) = p;
        if (hl == 0) gs[row] = den * inv;
    }
    __syncthreads();

    int ct = t >> 6;
    int lane = t & 63;
    int m = lane & 15, quad = lane >> 4;
    bf16x8 bfr[4];
    #pragma unroll
    for (int kk = 0; kk < 4; kk++)
        bfr[kk] = *(const bf16x8*)(Wb + (((kk * 8 + ct) * 64 + lane) << 3));
    float bl = blin[ct * 16 + m];
    float ssr = 0.f, qqr = 0.f;
    #pragma unroll
    for (int tile = 0; tile < 4; tile++) {
        f32x4 acc = (f32x4){0.f, 0.f, 0.f, 0.f};
        #pragma unroll
        for (int kk = 0; kk < 4; kk++) {
            bf16x8 af = *(const bf16x8*)(&At[(tile * 16 + m) * 136 + kk * 32 + quad * 8]);
            acc = __builtin_amdgcn_mfma_f32_16x16x32_bf16(af, bfr[kk], acc, 0, 0, 0);
        }
        int r0 = blockIdx.x * 64 + tile * 16;
        #pragma unroll
        for (int reg = 0; reg < 4; reg++) {
            int r = r0 + quad * 4 + reg;
            float g = gs[tile * 16 + quad * 4 + reg];
            float val = acc[reg] + bl * g;
            if (r < N_V) out[(size_t)r * 128 + ct * 16 + m] = val;
            ssr += val; qqr += val * val;   // invalid rows contribute exactly 0
        }
    }
    ssr += __shfl_xor(ssr, 16); qqr += __shfl_xor(qqr, 16);
    ssr += __shfl_xor(ssr, 32); qqr += __shfl_xor(qqr, 32);
    if (quad == 0) {
        partials[(size_t)blockIdx.x * 256 + ct * 16 + m] = ssr;
        partials[(size_t)blockIdx.x * 256 + 128 + ct * 16 + m] = qqr;
    }
}

// --- K5: parallel partials reduction: one wave per column ---
__global__ __launch_bounds__(64) void k_rstats(const float* __restrict__ partials,
                                               float* __restrict__ stats) {
    int c = blockIdx.x;          // 0..127
    int lane = threadIdx.x;      // 0..63
    float s = 0.f, q = 0.f;
    for (int b = lane; b < FUSED_BLOCKS; b += 64) {
        s += partials[(size_t)b * 256 + c];
        q += partials[(size_t)b * 256 + 128 + c];
    }
    #pragma unroll
    for (int off = 32; off; off >>= 1) {
        s += __shfl_down(s, off);
        q += __shfl_down(q, off);
    }
    if (lane == 0) {
        float mu = s * (1.f / N_V);
        float var = (q - s * mu) * (1.f / (N_V - 1));
        float sd = sqrtf(fmaxf(var, 0.f));
        stats[c] = mu;
        stats[128 + c] = 1.f / (sd + 1e-5f);
    }
}

// --- K6: normalize + ELU, in place, float4 ---
__global__ void k_finalize(float* __restrict__ out, const float* __restrict__ stats) {
    int i = blockIdx.x * blockDim.x + threadIdx.x;
    if (i >= N_V * 32) return;
    float4 v = ((float4*)out)[i];
    int c0 = (i * 4) & 127;
    float mu0 = stats[c0], mu1 = stats[c0 + 1], mu2 = stats[c0 + 2], mu3 = stats[c0 + 3];
    float is0 = stats[128 + c0], is1 = stats[128 + c0 + 1], is2 = stats[128 + c0 + 2], is3 = stats[128 + c0 + 3];
    v.x = (v.x - mu0) * is0; v.y = (v.y - mu1) * is1;
    v.z = (v.z - mu2) * is2; v.w = (v.w - mu3) * is3;
    v.x = v.x > 0.f ? v.x : expm1f(v.x);
    v.y = v.y > 0.f ? v.y : expm1f(v.y);
    v.z = v.z > 0.f ? v.z : expm1f(v.z);
    v.w = v.w > 0.f ? v.w : expm1f(v.w);
    ((float4*)out)[i] = v;
}

extern "C" void kernel_launch(void* const* d_in, const int* in_sizes, int n_in,
                              void* d_out, int out_size, void* d_ws, size_t ws_size,
                              hipStream_t stream) {
    const float* feat  = (const float*)d_in[0];
    const float* vtx   = (const float*)d_in[1];
    const int*   edges = (const int*)d_in[2];
    const int*   faces = (const int*)d_in[3];
    const float* W1   = (const float*)d_in[4];
    const float* b1   = (const float*)d_in[5];
    const float* W2   = (const float*)d_in[6];
    const float* b2   = (const float*)d_in[7];
    const float* Wlin = (const float*)d_in[8];
    const float* blin = (const float*)d_in[9];
    float* out = (float*)d_out;

    float* ws = (float*)d_ws;
    // Workspace: peak 1,708,320 floats (6.83 MB) < proven-safe 8.83 MB. Liveness:
    //   head_e   [0..100000)        : k_edge .. k_fused; stats ALIASES [0..256) (k_rstats..)
    //   head_f   [100000..200000)   : k_fn .. k_vnorm
    //   nrm      [200000..500000)   : k_vnorm .. k_edge
    //   partials [100000..500128)   : ALIAS head_f+nrm+pad — k_fused .. k_rstats
    //   fnbuf    [500128..1100128)  : k_fn .. k_vnorm; next_e ALIASES it (k_edge..k_fused)
    //   next_f   [1100128..1700128) : k_fn .. k_vnorm; wbuf ALIASES it (k_edge..k_fused)
    //   Wb       [1700128..1708320) : k_fn .. k_fused (16384 shorts)
    int*   head_e   = (int*)ws;                              // 100000
    int*   head_f   = (int*)(ws + 100000);                   // 100000
    float* nrm      = ws + 200000;                           // 300000
    float* partials = ws + 100000;                           // 400128 (alias)
    float* fnbuf    = ws + 500128;                           // 600000
    int*   next_e   = (int*)(ws + 500128);                   // 600000 (alias, fnbuf dead)
    int*   next_f   = (int*)(ws + 1100128);                  // 600000
    float* wbuf     = ws + 1100128;                          // 600000 (alias, next_f dead)
    unsigned short* Wb = (unsigned short*)(ws + 1700128);    // 16384 shorts
    float* stats    = ws;                                    // 256 (alias, head_e dead)

    // init both head arrays to -1
    hipMemsetAsync(d_ws, 0xFF, 200000 * sizeof(int), stream);

    k_fn<<<FACE_BLOCKS + PACK_BLOCKS, 256, 0, stream>>>(vtx, faces, Wlin, fnbuf,
                                                        head_f, next_f, Wb);
    k_vnorm<<<(N_V + 255) / 256, 256, 0, stream>>>(fnbuf, head_f, next_f, nrm);
    k_edge<<<EDGE_BLOCKS, 256, 0, stream>>>(vtx, edges, nrm, W1, b1, W2, b2,
                                            wbuf, head_e, next_e);
    k_fused<<<FUSED_BLOCKS, 512, 0, stream>>>(feat, edges, head_e, next_e, wbuf,
                                              Wb, blin, out, partials);
    k_rstats<<<128, 64, 0, stream>>>(partials, stats);
    k_finalize<<<(N_V * 32 + 255) / 256, 256, 0, stream>>>(out, stats);
}

// Round 8
// 280.170 us; speedup vs baseline: 2.3660x; 1.0335x over previous
//
#include <hip/hip_runtime.h>
#include <hip/hip_bf16.h>
#include <math.h>

#define N_V 100000
#define N_E 600000
#define N_F 200000
// CIN = COUT = 128, H = 32

typedef __attribute__((ext_vector_type(8))) short bf16x8;
typedef __attribute__((ext_vector_type(4))) float f32x4;

#define FUSED_BLOCKS 1563                   // ceil(100000/64); 64 rows per block
#define FACE_BLOCKS 782                     // ceil(200000/256)
#define EDGE_BLOCKS 2344                    // ceil(600000/256)
#define PACK_BLOCKS 64

__device__ __forceinline__ unsigned short f2bf(float f) {
    unsigned int u = __builtin_bit_cast(unsigned int, f);
    u += 0x7fffu + ((u >> 16) & 1u);   // round-to-nearest-even
    return (unsigned short)(u >> 16);
}

// --- K1: per-face normals (float4, streamed) + corner linked-list push + Wlin pack ---
__global__ void k_fn(const float* __restrict__ vtx, const int* __restrict__ faces,
                     const float* __restrict__ Wlin,
                     float4* __restrict__ fnbuf4,
                     int* __restrict__ head_f, int* __restrict__ next_f,
                     unsigned short* __restrict__ Wb) {
    int b = blockIdx.x;
    int t = threadIdx.x;
    if (b < FACE_BLOCKS) {
        int f = b * 256 + t;
        if (f >= N_F) return;
        int i0 = faces[f], i1 = faces[N_F + f], i2 = faces[2 * N_F + f];
        // push corners first so the exch latency overlaps the vtx gathers
        #pragma unroll
        for (int j = 0; j < 3; j++) {
            int v = (j == 0) ? i0 : (j == 1 ? i1 : i2);
            int c = 3 * f + j;
            int old = atomicExch(&head_f[v], c);
            next_f[c] = old;
        }
        float ax = vtx[3 * i0], ay = vtx[3 * i0 + 1], az = vtx[3 * i0 + 2];
        float bx = vtx[3 * i1] - ax, by = vtx[3 * i1 + 1] - ay, bz = vtx[3 * i1 + 2] - az;
        float cx = vtx[3 * i2] - ax, cy = vtx[3 * i2 + 1] - ay, cz = vtx[3 * i2 + 2] - az;
        float4 fn;
        fn.x = by * cz - bz * cy;
        fn.y = bz * cx - bx * cz;
        fn.z = bx * cy - by * cx;
        fn.w = 0.f;
        fnbuf4[f] = fn;
    } else {
        // pack Wlin (fp32 [128,128]) into bf16 MFMA B-fragment order
        int i = (b - FACE_BLOCKS) * 256 + t;   // 0..16383
        int j = i & 7;
        int lane = (i >> 3) & 63;
        int ct = (i >> 9) & 7;
        int kk = i >> 12;
        int k = kk * 32 + (lane >> 4) * 8 + j;
        int n = ct * 16 + (lane & 15);
        Wb[i] = f2bf(Wlin[k * 128 + n]);
    }
}

// --- K2: vertex normals via corner-list walk over float4 face normals ---
__global__ void k_vnorm(const float4* __restrict__ fnbuf4,
                        const int* __restrict__ head_f, const int* __restrict__ next_f,
                        float* __restrict__ nrm) {
    int v = blockIdx.x * 256 + threadIdx.x;
    if (v >= N_V) return;
    float nx = 0.f, ny = 0.f, nz = 0.f;
    int c = head_f[v];
    while (c >= 0) {
        float4 fn = fnbuf4[(unsigned)c / 3u];
        nx += fn.x; ny += fn.y; nz += fn.z;
        c = next_f[c];
    }
    float inv = 1.f / (sqrtf(nx * nx + ny * ny + nz * nz) + 1e-8f);
    nrm[3 * v] = nx * inv; nrm[3 * v + 1] = ny * inv; nrm[3 * v + 2] = nz * inv;
}

// --- K3: per-edge MLP -> packed node {src, next+1, w_bf16} in one uint2 ---
__global__ void k_edge(const float* __restrict__ vtx, const int* __restrict__ edges,
                       const float* __restrict__ nrm,
                       const float* __restrict__ W1, const float* __restrict__ b1,
                       const float* __restrict__ W2, const float* __restrict__ b2,
                       int* __restrict__ head_e, uint2* __restrict__ enode) {
    __shared__ float sW1[96], sb1[32], sW2[192], sb2[6];
    int t = threadIdx.x;
    if (t < 96)  sW1[t] = W1[t];
    if (t < 32)  sb1[t] = b1[t];
    if (t < 192) sW2[t] = W2[t];
    if (t < 6)   sb2[t] = b2[t];
    __syncthreads();
    int e = blockIdx.x * blockDim.x + t;
    if (e >= N_E) return;
    int s = edges[e], d = edges[N_E + e];
    int old = atomicExch(&head_e[d], e);      // issue early; latency hides under MLP
    float dx = vtx[3 * d] - vtx[3 * s];
    float dy = vtx[3 * d + 1] - vtx[3 * s + 1];
    float dz = vtx[3 * d + 2] - vtx[3 * s + 2];
    float nx = nrm[3 * s], ny = nrm[3 * s + 1], nz = nrm[3 * s + 2];
    float dp = dx * nx + dy * ny + dz * nz;
    float tx = dx - dp * nx, ty = dy - dp * ny, tz = dz - dp * nz;
    float th0 = sb2[0], th1 = sb2[1], th2 = sb2[2], th3 = sb2[3], th4 = sb2[4], th5 = sb2[5];
    #pragma unroll
    for (int j = 0; j < 32; j++) {
        float h = tx * sW1[j] + ty * sW1[32 + j] + tz * sW1[64 + j] + sb1[j];
        h = fmaxf(h, 0.f);
        const float* w2r = &sW2[j * 6];
        th0 += h * w2r[0]; th1 += h * w2r[1]; th2 += h * w2r[2];
        th3 += h * w2r[3]; th4 += h * w2r[4]; th5 += h * w2r[5];
    }
    // S symmetric; q = ||S t||^2
    float ux = th0 * tx + th1 * ty + th2 * tz;
    float uy = th1 * tx + th3 * ty + th4 * tz;
    float uz = th2 * tx + th4 * ty + th5 * tz;
    float q = ux * ux + uy * uy + uz * uz;
    float w = expf(-q);
    unsigned int w16 = f2bf(w);
    uint2 nd;
    nd.x = (unsigned int)(old + 1) | ((w16 & 0xFFFu) << 20);   // next+1 (20b) | w lo12
    nd.y = (unsigned int)s | ((w16 >> 12) << 17);              // src (17b) | w hi4
    enode[e] = nd;
}

// --- K4: FUSED aggregate + GEMM + bias + stats partials.
// Phase 1: each half-wave walks FOUR chains interleaved (4x memory-level parallelism).
__global__ __launch_bounds__(512) void k_fused(const float* __restrict__ feat,
                                               const int* __restrict__ head_e,
                                               const uint2* __restrict__ enode,
                                               const unsigned short* __restrict__ Wb,
                                               const float* __restrict__ blin,
                                               float* __restrict__ out,
                                               float* __restrict__ partials) {
    __shared__ __align__(16) unsigned short At[64 * 136];
    __shared__ float gs[64];
    int t = threadIdx.x;
    int hw = t >> 5;            // half-wave id 0..15
    int hl = t & 31;            // lane in half-wave
    int vb = blockIdx.x * 64 + hw * 4;   // this half-wave owns rows hw*4 .. hw*4+3

    float4 a0 = {0,0,0,0}, a1 = {0,0,0,0}, a2 = {0,0,0,0}, a3 = {0,0,0,0};
    float d0 = 0.f, d1 = 0.f, d2 = 0.f, d3 = 0.f;
    int e0 = (vb + 0 < N_V) ? head_e[vb + 0] : -1;
    int e1 = (vb + 1 < N_V) ? head_e[vb + 1] : -1;
    int e2 = (vb + 2 < N_V) ? head_e[vb + 2] : -1;
    int e3 = (vb + 3 < N_V) ? head_e[vb + 3] : -1;

    while ((e0 >= 0) || (e1 >= 0) || (e2 >= 0) || (e3 >= 0)) {
        if (e0 >= 0) {
            uint2 nd = enode[e0];
            unsigned int wb = (nd.x >> 20) | (((nd.y >> 17) & 0xFu) << 12);
            float w = __builtin_bit_cast(float, wb << 16);
            const float4 f = *(const float4*)(feat + (size_t)(nd.y & 0x1FFFFu) * 128 + 4 * hl);
            a0.x += w * f.x; a0.y += w * f.y; a0.z += w * f.z; a0.w += w * f.w;
            d0 += w;
            e0 = (int)(nd.x & 0xFFFFFu) - 1;
        }
        if (e1 >= 0) {
            uint2 nd = enode[e1];
            unsigned int wb = (nd.x >> 20) | (((nd.y >> 17) & 0xFu) << 12);
            float w = __builtin_bit_cast(float, wb << 16);
            const float4 f = *(const float4*)(feat + (size_t)(nd.y & 0x1FFFFu) * 128 + 4 * hl);
            a1.x += w * f.x; a1.y += w * f.y; a1.z += w * f.z; a1.w += w * f.w;
            d1 += w;
            e1 = (int)(nd.x & 0xFFFFFu) - 1;
        }
        if (e2 >= 0) {
            uint2 nd = enode[e2];
            unsigned int wb = (nd.x >> 20) | (((nd.y >> 17) & 0xFu) << 12);
            float w = __builtin_bit_cast(float, wb << 16);
            const float4 f = *(const float4*)(feat + (size_t)(nd.y & 0x1FFFFu) * 128 + 4 * hl);
            a2.x += w * f.x; a2.y += w * f.y; a2.z += w * f.z; a2.w += w * f.w;
            d2 += w;
            e2 = (int)(nd.x & 0xFFFFFu) - 1;
        }
        if (e3 >= 0) {
            uint2 nd = enode[e3];
            unsigned int wb = (nd.x >> 20) | (((nd.y >> 17) & 0xFu) << 12);
            float w = __builtin_bit_cast(float, wb << 16);
            const float4 f = *(const float4*)(feat + (size_t)(nd.y & 0x1FFFFu) * 128 + 4 * hl);
            a3.x += w * f.x; a3.y += w * f.y; a3.z += w * f.z; a3.w += w * f.w;
            d3 += w;
            e3 = (int)(nd.x & 0xFFFFFu) - 1;
        }
    }
    #pragma unroll
    for (int j = 0; j < 4; j++) {
        float4 a = (j == 0) ? a0 : (j == 1) ? a1 : (j == 2) ? a2 : a3;
        float dn = (j == 0) ? d0 : (j == 1) ? d1 : (j == 2) ? d2 : d3;
        float inv = 1.f / (dn + 1e-5f);
        ushort4 p;
        p.x = f2bf(a.x * inv); p.y = f2bf(a.y * inv);
        p.z = f2bf(a.z * inv); p.w = f2bf(a.w * inv);
        int row = hw * 4 + j;
        *(ushort4*)(&At[row * 136 + 4 * hl]) = p;
        if (hl == 0) gs[row] = dn * inv;
    }
    __syncthreads();

    // Phase 2: MFMA. wave id = column tile ct.
    int ct = t >> 6;
    int lane = t & 63;
    int m = lane & 15, quad = lane >> 4;
    bf16x8 bfr[4];
    #pragma unroll
    for (int kk = 0; kk < 4; kk++)
        bfr[kk] = *(const bf16x8*)(Wb + (((kk * 8 + ct) * 64 + lane) << 3));
    float bl = blin[ct * 16 + m];
    float ssr = 0.f, qqr = 0.f;
    #pragma unroll
    for (int tile = 0; tile < 4; tile++) {
        f32x4 acc = (f32x4){0.f, 0.f, 0.f, 0.f};
        #pragma unroll
        for (int kk = 0; kk < 4; kk++) {
            bf16x8 af = *(const bf16x8*)(&At[(tile * 16 + m) * 136 + kk * 32 + quad * 8]);
            acc = __builtin_amdgcn_mfma_f32_16x16x32_bf16(af, bfr[kk], acc, 0, 0, 0);
        }
        int r0 = blockIdx.x * 64 + tile * 16;
        #pragma unroll
        for (int reg = 0; reg < 4; reg++) {
            int r = r0 + quad * 4 + reg;
            float g = gs[tile * 16 + quad * 4 + reg];
            float val = acc[reg] + bl * g;
            if (r < N_V) out[(size_t)r * 128 + ct * 16 + m] = val;
            ssr += val; qqr += val * val;   // invalid rows contribute exactly 0
        }
    }
    ssr += __shfl_xor(ssr, 16); qqr += __shfl_xor(qqr, 16);
    ssr += __shfl_xor(ssr, 32); qqr += __shfl_xor(qqr, 32);
    if (quad == 0) {
        partials[(size_t)blockIdx.x * 256 + ct * 16 + m] = ssr;
        partials[(size_t)blockIdx.x * 256 + 128 + ct * 16 + m] = qqr;
    }
}

// --- K5: parallel partials reduction: one wave per column ---
__global__ __launch_bounds__(64) void k_rstats(const float* __restrict__ partials,
                                               float* __restrict__ stats) {
    int c = blockIdx.x;          // 0..127
    int lane = threadIdx.x;      // 0..63
    float s = 0.f, q = 0.f;
    for (int b = lane; b < FUSED_BLOCKS; b += 64) {
        s += partials[(size_t)b * 256 + c];
        q += partials[(size_t)b * 256 + 128 + c];
    }
    #pragma unroll
    for (int off = 32; off; off >>= 1) {
        s += __shfl_down(s, off);
        q += __shfl_down(q, off);
    }
    if (lane == 0) {
        float mu = s * (1.f / N_V);
        float var = (q - s * mu) * (1.f / (N_V - 1));
        float sd = sqrtf(fmaxf(var, 0.f));
        stats[c] = mu;
        stats[128 + c] = 1.f / (sd + 1e-5f);
    }
}

// --- K6: normalize + ELU, in place, float4 ---
__global__ void k_finalize(float* __restrict__ out, const float* __restrict__ stats) {
    int i = blockIdx.x * blockDim.x + threadIdx.x;
    if (i >= N_V * 32) return;
    float4 v = ((float4*)out)[i];
    int c0 = (i * 4) & 127;
    float mu0 = stats[c0], mu1 = stats[c0 + 1], mu2 = stats[c0 + 2], mu3 = stats[c0 + 3];
    float is0 = stats[128 + c0], is1 = stats[128 + c0 + 1], is2 = stats[128 + c0 + 2], is3 = stats[128 + c0 + 3];
    v.x = (v.x - mu0) * is0; v.y = (v.y - mu1) * is1;
    v.z = (v.z - mu2) * is2; v.w = (v.w - mu3) * is3;
    v.x = v.x > 0.f ? v.x : expm1f(v.x);
    v.y = v.y > 0.f ? v.y : expm1f(v.y);
    v.z = v.z > 0.f ? v.z : expm1f(v.z);
    v.w = v.w > 0.f ? v.w : expm1f(v.w);
    ((float4*)out)[i] = v;
}

extern "C" void kernel_launch(void* const* d_in, const int* in_sizes, int n_in,
                              void* d_out, int out_size, void* d_ws, size_t ws_size,
                              hipStream_t stream) {
    const float* feat  = (const float*)d_in[0];
    const float* vtx   = (const float*)d_in[1];
    const int*   edges = (const int*)d_in[2];
    const int*   faces = (const int*)d_in[3];
    const float* W1   = (const float*)d_in[4];
    const float* b1   = (const float*)d_in[5];
    const float* W2   = (const float*)d_in[6];
    const float* b2   = (const float*)d_in[7];
    const float* Wlin = (const float*)d_in[8];
    const float* blin = (const float*)d_in[9];
    float* out = (float*)d_out;

    float* ws = (float*)d_ws;
    // Workspace: peak 2,008,320 floats (8.03 MB) < proven-safe 8.83 MB. Liveness:
    //   head_e   [0..100000)        : memset .. k_fused; stats ALIASES [0..256) after
    //   nrm3     [100000..400000)   : k_vnorm .. k_edge
    //   partials [100000..500128)   : ALIAS nrm3+gap — k_fused .. k_rstats
    //   big region [500128..2000128): stage A/B = head_f(100k)+next_f(600k)+fnbuf4(800k)
    //                                 stage C/D = enode(1.2M) aliases its head
    //   Wb       [2000128..2008320) : k_fn .. k_fused (16384 shorts)
    int*   head_e   = (int*)ws;                              // 100000
    float* nrm3     = ws + 100000;                           // 300000
    float* partials = ws + 100000;                           // 400128 (alias)
    int*   head_f   = (int*)(ws + 500128);                   // 100000
    int*   next_f   = (int*)(ws + 600128);                   // 600000
    float4* fnbuf4  = (float4*)(ws + 1200128);               // 200000 float4
    uint2* enode    = (uint2*)(ws + 500128);                 // 600000 uint2 (alias)
    unsigned short* Wb = (unsigned short*)(ws + 2000128);    // 16384 shorts
    float* stats    = ws;                                    // 256 (alias, head_e dead)

    // init head arrays to -1 (two regions now)
    hipMemsetAsync(head_e, 0xFF, 100000 * sizeof(int), stream);
    hipMemsetAsync(head_f, 0xFF, 100000 * sizeof(int), stream);

    k_fn<<<FACE_BLOCKS + PACK_BLOCKS, 256, 0, stream>>>(vtx, faces, Wlin, fnbuf4,
                                                        head_f, next_f, Wb);
    k_vnorm<<<(N_V + 255) / 256, 256, 0, stream>>>(fnbuf4, head_f, next_f, nrm3);
    k_edge<<<EDGE_BLOCKS, 256, 0, stream>>>(vtx, edges, nrm3, W1, b1, W2, b2,
                                            head_e, enode);
    k_fused<<<FUSED_BLOCKS, 512, 0, stream>>>(feat, head_e, enode, Wb, blin,
                                              out, partials);
    k_rstats<<<128, 64, 0, stream>>>(partials, stats);
    k_finalize<<<(N_V * 32 + 255) / 256, 256, 0, stream>>>(out, stats);
}